// Round 6
// baseline (438.278 us; speedup 1.0000x reference)
//
#include <hip/hip_runtime.h>

typedef unsigned short u16;
typedef __attribute__((ext_vector_type(8))) short bf16x8;
typedef __attribute__((ext_vector_type(4))) float f32x4;

#define D_MODEL 1024
#define T_SEQ   2048
#define NB      4
#define NH      16
#define DKH     64

__device__ __forceinline__ u16 f2bf(float x) {
  union { float f; unsigned u; } v; v.f = x;
  unsigned r = v.u + 0x7fffu + ((v.u >> 16) & 1u);
  return (u16)(r >> 16);
}
__device__ __forceinline__ unsigned pack2(float a, float b) {
  return (unsigned)f2bf(a) | ((unsigned)f2bf(b) << 16);
}
__device__ __forceinline__ float fexp2(float x) {
#if __has_builtin(__builtin_amdgcn_exp2f)
  return __builtin_amdgcn_exp2f(x);
#else
  return __expf(x * 0.6931471805599453f);
#endif
}

// async global->LDS, 16B per lane. LDS dest = wave-uniform base + lane*16.
__device__ __forceinline__ void gload16(const void* g, void* l) {
  __builtin_amdgcn_global_load_lds(
      (const __attribute__((address_space(1))) unsigned*)g,
      (__attribute__((address_space(3))) unsigned*)l, 16, 0, 0);
}

// ---------------- cast 4 weight matrices fp32 -> bf16 ----------------
__global__ void cast_w4(const float* __restrict__ s0, const float* __restrict__ s1,
                        const float* __restrict__ s2, const float* __restrict__ s3,
                        u16* __restrict__ o0, u16* __restrict__ o1,
                        u16* __restrict__ o2, u16* __restrict__ o3) {
  const int which = blockIdx.y;
  const float* s = which == 0 ? s0 : which == 1 ? s1 : which == 2 ? s2 : s3;
  u16* o = which == 0 ? o0 : which == 1 ? o1 : which == 2 ? o2 : o3;
  int i = ((int)blockIdx.x * 256 + (int)threadIdx.x) * 4;
  float4 v = *(const float4*)(s + i);
  uint2 u; u.x = pack2(v.x, v.y); u.y = pack2(v.z, v.w);
  *(uint2*)(o + i) = u;
}

// XCD-aware block decode: bid%8 = XCD residue; all 8 n-tiles of an m-band share
// a residue -> per-XCD L2 working set = 1 A band + B (stays resident).
__device__ __forceinline__ void xcd_decode(int bid, int& m0, int& n0) {
  m0 = ((bid & 7) + ((bid >> 6) << 3)) << 7;
  n0 = ((bid >> 3) & 7) << 7;
}

// ---------------- fused QKV projection: cast A in staging, B async ----------------
// grid (512, 1, 3); z selects (q,k,v). C = A@W^T + bias, bf16 out.
// Q output pre-scaled by (1/8)*log2(e) so attention softmax is a bare exp2.
__global__ __launch_bounds__(256) void gemm_qkv(
    const float* __restrict__ qin, const float* __restrict__ kin, const float* __restrict__ vin,
    const u16* __restrict__ wq, const u16* __restrict__ wk, const u16* __restrict__ wv,
    const float* __restrict__ bqp, const float* __restrict__ bkp, const float* __restrict__ bvp,
    u16* __restrict__ Xq, u16* __restrict__ Xk, u16* __restrict__ Xv) {
  const int z = blockIdx.z;
  const float* A = z == 0 ? qin : z == 1 ? kin : vin;
  const u16* W = z == 0 ? wq : z == 1 ? wk : wv;
  const float* bias = z == 0 ? bqp : z == 1 ? bkp : bvp;
  u16* C = z == 0 ? Xq : z == 1 ? Xk : Xv;
  const float osc = z == 0 ? 0.18033688011112042f : 1.0f;  // log2(e)/8
  const int K = 1024, N = 1024;

  __shared__ __align__(16) u16 As[128 * 72];   // VALU-staged (cast), padded stride
  __shared__ __align__(16) u16 Bs[128 * 64];   // async, xor-swizzled
  const int tid = threadIdx.x;
  const int w = tid >> 6, lane = tid & 63;
  const int wm = w & 1, wn = w >> 1;
  const int l15 = lane & 15, quad = lane >> 4;
  int m0, n0; xcd_decode(blockIdx.x, m0, n0);
  const int srow = tid >> 3;
  const int scol = (tid & 7) * 8;
  const int lrow = lane >> 3;
  const int lcol = ((lane & 7) ^ lrow) * 8;

  const u16* gB = W + (size_t)(n0 + w * 32 + lrow) * K + lcol;
  u16* lB = Bs + w * 32 * 64;

  f32x4 zero4 = {0.f, 0.f, 0.f, 0.f};
  f32x4 acc[4][4];
#pragma unroll
  for (int i = 0; i < 4; ++i)
#pragma unroll
    for (int j = 0; j < 4; ++j) acc[i][j] = zero4;

  for (int kb = 0; kb < K; kb += 64) {
    uint4 ra[4];
#pragma unroll
    for (int r = 0; r < 4; ++r) {
      const float* p = A + (size_t)(m0 + r * 32 + srow) * K + kb + scol;
      float4 x = *(const float4*)p;
      float4 y = *(const float4*)(p + 4);
      ra[r].x = pack2(x.x, x.y); ra[r].y = pack2(x.z, x.w);
      ra[r].z = pack2(y.x, y.y); ra[r].w = pack2(y.z, y.w);
    }
    __syncthreads();
#pragma unroll
    for (int t = 0; t < 4; ++t) gload16(gB + kb + t * 8 * K, lB + t * 512);
#pragma unroll
    for (int r = 0; r < 4; ++r)
      *(uint4*)(As + (r * 32 + srow) * 72 + scol) = ra[r];
    __syncthreads();

#pragma unroll
    for (int ks = 0; ks < 2; ++ks) {
      const int sB = (((ks * 4 + quad) ^ (l15 & 7)) * 8);
      bf16x8 af[4], bfr[4];
#pragma unroll
      for (int i = 0; i < 4; ++i)
        af[i] = *(const bf16x8*)(As + (wm * 64 + i * 16 + l15) * 72 + ks * 32 + quad * 8);
#pragma unroll
      for (int i = 0; i < 4; ++i)
        bfr[i] = *(const bf16x8*)(Bs + (wn * 64 + i * 16 + l15) * 64 + sB);
#pragma unroll
      for (int mi = 0; mi < 4; ++mi)
#pragma unroll
        for (int ni = 0; ni < 4; ++ni)
          acc[mi][ni] = __builtin_amdgcn_mfma_f32_16x16x32_bf16(af[mi], bfr[ni], acc[mi][ni], 0, 0, 0);
    }
  }

#pragma unroll
  for (int ni = 0; ni < 4; ++ni) {
    int col = n0 + wn * 64 + ni * 16 + l15;
    float bv = bias[col];
#pragma unroll
    for (int mi = 0; mi < 4; ++mi) {
      int row = m0 + wm * 64 + mi * 16 + quad * 4;
#pragma unroll
      for (int r = 0; r < 4; ++r)
        C[(size_t)(row + r) * N + col] = f2bf((acc[mi][ni][r] + bv) * osc);
    }
  }
}

// ---------------- O-projection GEMM (bf16 A, full async staging) ----------------
__global__ __launch_bounds__(256) void gemm_nt_f32out(const u16* __restrict__ Ab,
                                                      const u16* __restrict__ W,
                                                      const float* __restrict__ bias,
                                                      float* __restrict__ Cp,
                                                      int M, int N, int K) {
  __shared__ __align__(16) u16 As[128 * 64];
  __shared__ __align__(16) u16 Bs[128 * 64];
  const int tid = threadIdx.x;
  const int w = tid >> 6, lane = tid & 63;
  const int wm = w & 1, wn = w >> 1;
  const int l15 = lane & 15, quad = lane >> 4;
  int m0, n0; xcd_decode(blockIdx.x, m0, n0);
  const int lrow = lane >> 3;
  const int lcol = ((lane & 7) ^ lrow) * 8;

  const u16* gA = Ab + (size_t)(m0 + w * 32 + lrow) * K + lcol;
  const u16* gB = W  + (size_t)(n0 + w * 32 + lrow) * K + lcol;
  u16* lA = As + w * 32 * 64;
  u16* lB = Bs + w * 32 * 64;

  f32x4 zero4 = {0.f, 0.f, 0.f, 0.f};
  f32x4 acc[4][4];
#pragma unroll
  for (int i = 0; i < 4; ++i)
#pragma unroll
    for (int j = 0; j < 4; ++j) acc[i][j] = zero4;

  for (int kb = 0; kb < K; kb += 64) {
    __syncthreads();
#pragma unroll
    for (int t = 0; t < 4; ++t) gload16(gA + kb + t * 8 * K, lA + t * 512);
#pragma unroll
    for (int t = 0; t < 4; ++t) gload16(gB + kb + t * 8 * K, lB + t * 512);
    __syncthreads();

#pragma unroll
    for (int ks = 0; ks < 2; ++ks) {
      const int sA = (((ks * 4 + quad) ^ (l15 & 7)) * 8);
      bf16x8 af[4], bfr[4];
#pragma unroll
      for (int i = 0; i < 4; ++i)
        af[i] = *(const bf16x8*)(As + (wm * 64 + i * 16 + l15) * 64 + sA);
#pragma unroll
      for (int i = 0; i < 4; ++i)
        bfr[i] = *(const bf16x8*)(Bs + (wn * 64 + i * 16 + l15) * 64 + sA);
#pragma unroll
      for (int mi = 0; mi < 4; ++mi)
#pragma unroll
        for (int ni = 0; ni < 4; ++ni)
          acc[mi][ni] = __builtin_amdgcn_mfma_f32_16x16x32_bf16(af[mi], bfr[ni], acc[mi][ni], 0, 0, 0);
    }
  }

#pragma unroll
  for (int ni = 0; ni < 4; ++ni) {
    int col = n0 + wn * 64 + ni * 16 + l15;
    float bv = bias[col];
#pragma unroll
    for (int mi = 0; mi < 4; ++mi) {
      int row = m0 + wm * 64 + mi * 16 + quad * 4;
#pragma unroll
      for (int r = 0; r < 4; ++r)
        Cp[(size_t)(row + r) * N + col] = acc[mi][ni][r] + bv;
    }
  }
}

// ---------------- causal flash attention v6: intra-block split-K ----------------
// grid (8, NH, NB) = 512 blocks, 512 threads (8 waves). Waves 0-3 (half 0) do
// even k-tiles, waves 4-7 (half 1) odd k-tiles of the same q-tile; q-tile pair
// (15-x, x) -> every half does exactly 17 tiles. No-max exp2 softmax => halves'
// partial (O, l) merge by pure addition via LDS at phase end.
// Per half: K async-DMA dbuf (xor-swizzled), V reg-prefetch -> kappa+xor Vt dbuf.
// LDS exactly 64 KB -> 2 blocks/CU -> 16 waves/CU.
__global__ __launch_bounds__(512, 4) void attn_fwd(const u16* __restrict__ Xq,
                                                   const u16* __restrict__ Xk,
                                                   const u16* __restrict__ Xv,
                                                   u16* __restrict__ O) {
  __shared__ __align__(16) char smem[65536];
  // per half h at h*32768: Kt 2x4096 u16 (16KB), Vt 2x4096 u16 (16KB)
  // merge overlay: MO floats on half-1 region (32KB), ML floats on half-0 Vt.

  const int xp = blockIdx.x;                // 0..7
  const int h = blockIdx.y, b = blockIdx.z;
  const int tid = threadIdx.x;
  const int w = tid >> 6, lane = tid & 63;
  const int half = w >> 2, wl = w & 3;
  const int l15 = lane & 15, quad = lane >> 4;
  const size_t base = (size_t)b * T_SEQ * D_MODEL;
  const int hd = h * DKH;

  u16* KtH = (u16*)(smem + half * 32768);
  u16* VtH = (u16*)(smem + half * 32768 + 16384);
  float* ML = (float*)(smem + 16384);
  float* MO = (float*)(smem + 32768);

  // K DMA mapping: 2 gload16/wave/tile, xor-swizzled source dim-blocks
  const int krow = lane >> 3;
  const int kcol = ((lane & 7) ^ krow) * 8;
  const u16* gK = Xk + base + (size_t)(wl * 16 + krow) * D_MODEL + hd + kcol;
  // V staging: thread owns key=lane, dims wl*16..+16; kappa-permuted col + xor blk
  const int vkey = lane;
  const int skey = (vkey & 0x20) | ((vkey & 0xC) << 1) | ((vkey & 0x10) >> 2) | (vkey & 3);
  const int scb = skey >> 3, sci = skey & 7;
  const u16* gV = Xv + base + (size_t)vkey * D_MODEL + hd + wl * 16;

  bf16x8 bones;
#pragma unroll
  for (int i = 0; i < 8; ++i) bones[i] = (short)0x3F80;  // bf16 1.0

  f32x4 zero4 = {0.f, 0.f, 0.f, 0.f};
  int tcnt = 0;

  // preload first tile (k0 = half*64): K DMA -> buf0, V -> regs
  {
    const u16* gk0 = gK + (size_t)(half * 64) * D_MODEL;
    gload16(gk0, KtH + (wl * 16) * 64);
    gload16(gk0 + (size_t)8 * D_MODEL, KtH + (wl * 16 + 8) * 64);
  }
  const u16* gv0 = gV + (size_t)(half * 64) * D_MODEL;
  uint4 va0 = *(const uint4*)gv0;
  uint4 va1 = *(const uint4*)(gv0 + 8);

  for (int ph = 0; ph < 2; ++ph) {
    const int qt = ph ? xp : 15 - xp;       // heavy tile first
    const int q0 = qt << 7;
    const int rowb0 = q0 + wl * 32;

    bf16x8 bq[2][2];
#pragma unroll
    for (int mi = 0; mi < 2; ++mi)
#pragma unroll
      for (int ks = 0; ks < 2; ++ks)
        bq[mi][ks] = *(const bf16x8*)(Xq + base + (size_t)(rowb0 + mi * 16 + l15) * D_MODEL
                                      + hd + ks * 32 + quad * 8);

    f32x4 o[4][2], ol[2];
#pragma unroll
    for (int di = 0; di < 4; ++di)
#pragma unroll
      for (int mi = 0; mi < 2; ++mi) o[di][mi] = zero4;
#pragma unroll
    for (int mi = 0; mi < 2; ++mi) ol[mi] = zero4;

    const int cnt = qt + 1;                 // local tiles this phase (per half)

    // half-1's cross-phase K prefetch was skipped (merge clobbers its region):
    // re-issue here; drained by iteration-0's barrier.
    if (ph == 1 && half == 1) {
      const int fb = tcnt & 1;
      const u16* gk1 = gK + (size_t)64 * D_MODEL;
      gload16(gk1, KtH + fb * 4096 + (wl * 16) * 64);
      gload16(gk1 + (size_t)8 * D_MODEL, KtH + fb * 4096 + (wl * 16 + 8) * 64);
    }

    for (int i = 0; i < cnt; ++i, ++tcnt) {
      const int k0 = (half + 2 * i) * 64;
      const int buf = tcnt & 1;
      u16* ktb = KtH + buf * 4096;
      u16* vtb = VtH + buf * 4096;

      // stage Vt[buf] from held regs
      {
        union { uint4 u; u16 hh[8]; } u0, u1;
        u0.u = va0; u1.u = va1;
#pragma unroll
        for (int ii = 0; ii < 8; ++ii) {
          vtb[(wl * 16 + ii) * 64 + ((scb ^ ii) << 3) + sci] = u0.hh[ii];
          vtb[(wl * 16 + 8 + ii) * 64 + ((scb ^ ii) << 3) + sci] = u1.hh[ii];
        }
      }
      __syncthreads();   // K DMA drained + Vt visible (single barrier per tile)

      // prefetch next local tile (k0+128) or phase-1's first tile
      const bool inph = (i + 1 < cnt);
      if (inph || ph == 0) {
        const int k0n = inph ? k0 + 128 : half * 64;
        if (inph || half == 0) {            // half-1 cross-phase K handled above
          const u16* gk2 = gK + (size_t)k0n * D_MODEL;
          u16* ktn = KtH + (1 - buf) * 4096;
          gload16(gk2, ktn + (wl * 16) * 64);
          gload16(gk2 + (size_t)8 * D_MODEL, ktn + (wl * 16 + 8) * 64);
        }
        const u16* gv2 = gV + (size_t)k0n * D_MODEL;
        va0 = *(const uint4*)gv2;
        va1 = *(const uint4*)(gv2 + 8);
      }

      // S^T = K Q^T, K A-frags from swizzled LDS
      f32x4 st[4][2];
#pragma unroll
      for (int ni = 0; ni < 4; ++ni) {
        const u16* kr = ktb + (ni * 16 + l15) * 64;
        bf16x8 a0 = *(const bf16x8*)(kr + ((quad ^ (l15 & 7)) << 3));
        bf16x8 a1 = *(const bf16x8*)(kr + (((4 + quad) ^ (l15 & 7)) << 3));
#pragma unroll
        for (int mi = 0; mi < 2; ++mi) {
          f32x4 t = zero4;
          t = __builtin_amdgcn_mfma_f32_16x16x32_bf16(a0, bq[mi][0], t, 0, 0, 0);
          t = __builtin_amdgcn_mfma_f32_16x16x32_bf16(a1, bq[mi][1], t, 0, 0, 0);
          st[ni][mi] = t;
        }
      }

      // causal mask + bare-exp2 softmax + in-lane pack (kappa order)
      bf16x8 bp[2][2];
#pragma unroll
      for (int mi = 0; mi < 2; ++mi) {
        const int qa = rowb0 + mi * 16 + l15;
        if (k0 + 63 > rowb0 + mi * 16) {    // wave-uniform: diagonal-ish tiles
#pragma unroll
          for (int ni = 0; ni < 4; ++ni)
#pragma unroll
            for (int r = 0; r < 4; ++r)
              if (k0 + ni * 16 + quad * 4 + r > qa) st[ni][mi][r] = -1e30f;
        }
        float p[4][4];
#pragma unroll
        for (int ni = 0; ni < 4; ++ni)
#pragma unroll
          for (int r = 0; r < 4; ++r)
            p[ni][r] = fexp2(st[ni][mi][r]);
#pragma unroll
        for (int js = 0; js < 2; ++js) {
          union { bf16x8 v; unsigned d[4]; } ub;
          ub.d[0] = pack2(p[2 * js][0], p[2 * js][1]);
          ub.d[1] = pack2(p[2 * js][2], p[2 * js][3]);
          ub.d[2] = pack2(p[2 * js + 1][0], p[2 * js + 1][1]);
          ub.d[3] = pack2(p[2 * js + 1][2], p[2 * js + 1][3]);
          bp[mi][js] = ub.v;
        }
      }

      // O^T += V^T P^T ; ol += 1 P^T
#pragma unroll
      for (int js = 0; js < 2; ++js) {
        bf16x8 av[4];
#pragma unroll
        for (int di = 0; di < 4; ++di)
          av[di] = *(const bf16x8*)(vtb + (di * 16 + l15) * 64
                                    + (((js * 4 + quad) ^ (l15 & 7)) << 3));
#pragma unroll
        for (int di = 0; di < 4; ++di)
#pragma unroll
          for (int mi = 0; mi < 2; ++mi)
            o[di][mi] = __builtin_amdgcn_mfma_f32_16x16x32_bf16(av[di], bp[mi][js], o[di][mi], 0, 0, 0);
#pragma unroll
        for (int mi = 0; mi < 2; ++mi)
          ol[mi] = __builtin_amdgcn_mfma_f32_16x16x32_bf16(bones, bp[mi][js], ol[mi], 0, 0, 0);
      }
    }

    // ---- merge halves (partial sums add directly; no-max softmax) ----
    __syncthreads();                         // B1: all PV reads done
    if (half == 1) {
#pragma unroll
      for (int mi = 0; mi < 2; ++mi) {
        const int ql = wl * 32 + mi * 16 + l15;
        if (quad == 0) ML[ql] = ol[mi][0];
#pragma unroll
        for (int di = 0; di < 4; ++di)
#pragma unroll
          for (int r = 0; r < 4; ++r) {
            const int d = di * 16 + quad * 4 + r;
            MO[ql * 64 + (d ^ ((ql & 7) << 3))] = o[di][mi][r];
          }
      }
    }
    __syncthreads();                         // B2: merge data visible
    if (half == 0) {
#pragma unroll
      for (int mi = 0; mi < 2; ++mi) {
        const int ql = wl * 32 + mi * 16 + l15;
        const float inv = 1.0f / (ol[mi][0] + ML[ql]);
        const size_t qa = q0 + ql;
#pragma unroll
        for (int di = 0; di < 4; ++di) {
          float t[4];
#pragma unroll
          for (int r = 0; r < 4; ++r) {
            const int d = di * 16 + quad * 4 + r;
            t[r] = (o[di][mi][r] + MO[ql * 64 + (d ^ ((ql & 7) << 3))]) * inv;
          }
          uint2 s2;
          s2.x = pack2(t[0], t[1]);
          s2.y = pack2(t[2], t[3]);
          *(uint2*)(O + base + qa * D_MODEL + hd + di * 16 + quad * 4) = s2;
        }
      }
    }
    __syncthreads();                         // B3: merge reads done before reuse
  }
}

// ---------------- launch ----------------
extern "C" void kernel_launch(void* const* d_in, const int* in_sizes, int n_in,
                              void* d_out, int out_size, void* d_ws, size_t ws_size,
                              hipStream_t stream) {
  const float* q   = (const float*)d_in[0];
  const float* k   = (const float*)d_in[1];
  const float* v   = (const float*)d_in[2];
  const float* w_q = (const float*)d_in[4];  const float* b_q = (const float*)d_in[5];
  const float* w_k = (const float*)d_in[6];  const float* b_k = (const float*)d_in[7];
  const float* w_v = (const float*)d_in[8];  const float* b_v = (const float*)d_in[9];
  const float* w_o = (const float*)d_in[10]; const float* b_o = (const float*)d_in[11];

  u16* ws = (u16*)d_ws;
  const size_t NTD = (size_t)NB * T_SEQ * D_MODEL;   // 8388608
  const size_t WSZ = (size_t)D_MODEL * D_MODEL;      // 1048576
  u16* wqb = ws;
  u16* wkb = wqb + WSZ;
  u16* wvb = wkb + WSZ;
  u16* wob = wvb + WSZ;
  u16* Xq  = wob + WSZ;
  u16* Xk  = Xq + NTD;
  u16* Xv  = Xk + NTD;
  u16* Ob  = Xv + NTD;
  // total ws: 4*2MB + 4*16.78MB = 75.5 MB

  cast_w4<<<dim3(WSZ / 1024, 4), 256, 0, stream>>>(w_q, w_k, w_v, w_o, wqb, wkb, wvb, wob);

  gemm_qkv<<<dim3(512, 1, 3), 256, 0, stream>>>(q, k, v, wqb, wkb, wvb,
                                                b_q, b_k, b_v, Xq, Xk, Xv);

  attn_fwd<<<dim3(8, NH, NB), 512, 0, stream>>>(Xq, Xk, Xv, Ob);

  gemm_nt_f32out<<<dim3(512), 256, 0, stream>>>(Ob, wob, b_o, (float*)d_out,
                                                8192, 1024, 1024);
}

// Round 7
// 359.087 us; speedup vs baseline: 1.2205x; 1.2205x over previous
//
#include <hip/hip_runtime.h>

typedef unsigned short u16;
typedef __attribute__((ext_vector_type(8))) short bf16x8;
typedef __attribute__((ext_vector_type(4))) float f32x4;

#define D_MODEL 1024
#define T_SEQ   2048
#define NB      4
#define NH      16
#define DKH     64

__device__ __forceinline__ u16 f2bf(float x) {
  union { float f; unsigned u; } v; v.f = x;
  unsigned r = v.u + 0x7fffu + ((v.u >> 16) & 1u);
  return (u16)(r >> 16);
}
__device__ __forceinline__ unsigned pack2(float a, float b) {
  return (unsigned)f2bf(a) | ((unsigned)f2bf(b) << 16);
}
__device__ __forceinline__ float fexp2(float x) {
#if __has_builtin(__builtin_amdgcn_exp2f)
  return __builtin_amdgcn_exp2f(x);
#else
  return __expf(x * 0.6931471805599453f);
#endif
}

// async global->LDS, 16B per lane. LDS dest = wave-uniform base + lane*16.
__device__ __forceinline__ void gload16(const void* g, void* l) {
  __builtin_amdgcn_global_load_lds(
      (const __attribute__((address_space(1))) unsigned*)g,
      (__attribute__((address_space(3))) unsigned*)l, 16, 0, 0);
}

// ---------------- cast 4 weight matrices fp32 -> bf16 ----------------
__global__ void cast_w4(const float* __restrict__ s0, const float* __restrict__ s1,
                        const float* __restrict__ s2, const float* __restrict__ s3,
                        u16* __restrict__ o0, u16* __restrict__ o1,
                        u16* __restrict__ o2, u16* __restrict__ o3) {
  const int which = blockIdx.y;
  const float* s = which == 0 ? s0 : which == 1 ? s1 : which == 2 ? s2 : s3;
  u16* o = which == 0 ? o0 : which == 1 ? o1 : which == 2 ? o2 : o3;
  int i = ((int)blockIdx.x * 256 + (int)threadIdx.x) * 4;
  float4 v = *(const float4*)(s + i);
  uint2 u; u.x = pack2(v.x, v.y); u.y = pack2(v.z, v.w);
  *(uint2*)(o + i) = u;
}

// ---------------- fused QKV projection, 128x256 tiles ----------------
// grid (64, 4, 3); z selects (q,k,v). C = A@W^T + bias, bf16 out.
// A: fp32, VALU-cast during staging (padded stride 72). B: async DMA,
// xor-swizzled, 256 rows. Q output pre-scaled by log2(e)/8 (bare-exp2 softmax).
__global__ __launch_bounds__(256) void gemm_qkv(
    const float* __restrict__ qin, const float* __restrict__ kin, const float* __restrict__ vin,
    const u16* __restrict__ wq, const u16* __restrict__ wk, const u16* __restrict__ wv,
    const float* __restrict__ bqp, const float* __restrict__ bkp, const float* __restrict__ bvp,
    u16* __restrict__ Xq, u16* __restrict__ Xk, u16* __restrict__ Xv) {
  const int z = blockIdx.z;
  const float* A = z == 0 ? qin : z == 1 ? kin : vin;
  const u16* W = z == 0 ? wq : z == 1 ? wk : wv;
  const float* bias = z == 0 ? bqp : z == 1 ? bkp : bvp;
  u16* C = z == 0 ? Xq : z == 1 ? Xk : Xv;
  const float osc = z == 0 ? 0.18033688011112042f : 1.0f;  // log2(e)/8
  const int K = 1024, N = 1024;

  __shared__ __align__(16) u16 As[128 * 72];   // 18 KB, VALU-staged (cast)
  __shared__ __align__(16) u16 Bs[256 * 64];   // 32 KB, async, xor-swizzled
  const int tid = threadIdx.x;
  const int w = tid >> 6, lane = tid & 63;
  const int wm = w & 1, wn = w >> 1;
  const int l15 = lane & 15, quad = lane >> 4;
  const int m0 = blockIdx.x * 128, n0 = blockIdx.y * 256;
  const int srow = tid >> 3;                  // 0..31
  const int scol = (tid & 7) * 8;             // 0..56
  const int lrow = lane >> 3;                 // 0..7
  const int lcol = ((lane & 7) ^ lrow) * 8;   // xor-swizzled source col block

  const u16* gB = W + (size_t)(n0 + w * 64 + lrow) * K + lcol;
  u16* lB = Bs + w * 64 * 64;                 // wave stages 64 B-rows

  f32x4 zero4 = {0.f, 0.f, 0.f, 0.f};
  f32x4 acc[4][8];
#pragma unroll
  for (int i = 0; i < 4; ++i)
#pragma unroll
    for (int j = 0; j < 8; ++j) acc[i][j] = zero4;

  for (int kb = 0; kb < K; kb += 64) {
    uint4 ra[4];
#pragma unroll
    for (int r = 0; r < 4; ++r) {
      const float* p = A + (size_t)(m0 + r * 32 + srow) * K + kb + scol;
      float4 x = *(const float4*)p;
      float4 y = *(const float4*)(p + 4);
      ra[r].x = pack2(x.x, x.y); ra[r].y = pack2(x.z, x.w);
      ra[r].z = pack2(y.x, y.y); ra[r].w = pack2(y.z, y.w);
    }
    __syncthreads();   // prev iter's ds_reads done
#pragma unroll
    for (int t = 0; t < 8; ++t) gload16(gB + kb + (size_t)t * 8 * K, lB + t * 512);
#pragma unroll
    for (int r = 0; r < 4; ++r)
      *(uint4*)(As + (r * 32 + srow) * 72 + scol) = ra[r];
    __syncthreads();   // drains vmcnt + lgkm -> tiles ready

#pragma unroll
    for (int ks = 0; ks < 2; ++ks) {
      bf16x8 af[4], bfr[8];
#pragma unroll
      for (int i = 0; i < 4; ++i)
        af[i] = *(const bf16x8*)(As + (wm * 64 + i * 16 + l15) * 72 + ks * 32 + quad * 8);
      const int sB = (((ks * 4 + quad) ^ (l15 & 7)) * 8);
#pragma unroll
      for (int i = 0; i < 8; ++i)
        bfr[i] = *(const bf16x8*)(Bs + (wn * 128 + i * 16 + l15) * 64 + sB);
#pragma unroll
      for (int mi = 0; mi < 4; ++mi)
#pragma unroll
        for (int ni = 0; ni < 8; ++ni)
          acc[mi][ni] = __builtin_amdgcn_mfma_f32_16x16x32_bf16(af[mi], bfr[ni], acc[mi][ni], 0, 0, 0);
    }
  }

#pragma unroll
  for (int ni = 0; ni < 8; ++ni) {
    int col = n0 + wn * 128 + ni * 16 + l15;
    float bv = bias[col];
#pragma unroll
    for (int mi = 0; mi < 4; ++mi) {
      int row = m0 + wm * 64 + mi * 16 + quad * 4;
#pragma unroll
      for (int r = 0; r < 4; ++r)
        C[(size_t)(row + r) * N + col] = f2bf((acc[mi][ni][r] + bv) * osc);
    }
  }
}

// ---------------- O-projection GEMM (bf16 A, full async staging, 128x128) ----------------
__global__ __launch_bounds__(256) void gemm_nt_f32out(const u16* __restrict__ Ab,
                                                      const u16* __restrict__ W,
                                                      const float* __restrict__ bias,
                                                      float* __restrict__ Cp,
                                                      int M, int N, int K) {
  __shared__ __align__(16) u16 As[128 * 64];
  __shared__ __align__(16) u16 Bs[128 * 64];
  const int tid = threadIdx.x;
  const int w = tid >> 6, lane = tid & 63;
  const int wm = w & 1, wn = w >> 1;
  const int l15 = lane & 15, quad = lane >> 4;
  const int m0 = blockIdx.x * 128, n0 = blockIdx.y * 128;
  const int lrow = lane >> 3;
  const int lcol = ((lane & 7) ^ lrow) * 8;

  const u16* gA = Ab + (size_t)(m0 + w * 32 + lrow) * K + lcol;
  const u16* gB = W  + (size_t)(n0 + w * 32 + lrow) * K + lcol;
  u16* lA = As + w * 32 * 64;
  u16* lB = Bs + w * 32 * 64;

  f32x4 zero4 = {0.f, 0.f, 0.f, 0.f};
  f32x4 acc[4][4];
#pragma unroll
  for (int i = 0; i < 4; ++i)
#pragma unroll
    for (int j = 0; j < 4; ++j) acc[i][j] = zero4;

  for (int kb = 0; kb < K; kb += 64) {
    __syncthreads();
#pragma unroll
    for (int t = 0; t < 4; ++t) gload16(gA + kb + t * 8 * K, lA + t * 512);
#pragma unroll
    for (int t = 0; t < 4; ++t) gload16(gB + kb + t * 8 * K, lB + t * 512);
    __syncthreads();

#pragma unroll
    for (int ks = 0; ks < 2; ++ks) {
      const int sA = (((ks * 4 + quad) ^ (l15 & 7)) * 8);
      bf16x8 af[4], bfr[4];
#pragma unroll
      for (int i = 0; i < 4; ++i)
        af[i] = *(const bf16x8*)(As + (wm * 64 + i * 16 + l15) * 64 + sA);
#pragma unroll
      for (int i = 0; i < 4; ++i)
        bfr[i] = *(const bf16x8*)(Bs + (wn * 64 + i * 16 + l15) * 64 + sA);
#pragma unroll
      for (int mi = 0; mi < 4; ++mi)
#pragma unroll
        for (int ni = 0; ni < 4; ++ni)
          acc[mi][ni] = __builtin_amdgcn_mfma_f32_16x16x32_bf16(af[mi], bfr[ni], acc[mi][ni], 0, 0, 0);
    }
  }

#pragma unroll
  for (int ni = 0; ni < 4; ++ni) {
    int col = n0 + wn * 64 + ni * 16 + l15;
    float bv = bias[col];
#pragma unroll
    for (int mi = 0; mi < 4; ++mi) {
      int row = m0 + wm * 64 + mi * 16 + quad * 4;
#pragma unroll
      for (int r = 0; r < 4; ++r)
        Cp[(size_t)(row + r) * N + col] = acc[mi][ni][r] + bv;
    }
  }
}

// ---------------- causal flash attention v7: intra-block split-K ----------------
// Identical structure to r6 (correctness-verified). Fix: __launch_bounds__(512,2)
// so the compiler is NOT capped at 64 VGPRs (r6's 300 MB of scratch spills).
// Natural VGPR ~100-115 <= 128 -> 2 blocks/CU (16 waves) at 64 KB LDS.
__global__ __launch_bounds__(512, 2) void attn_fwd(const u16* __restrict__ Xq,
                                                   const u16* __restrict__ Xk,
                                                   const u16* __restrict__ Xv,
                                                   u16* __restrict__ O) {
  __shared__ __align__(16) char smem[65536];
  // per half h at h*32768: Kt 2x4096 u16 (16KB), Vt 2x4096 u16 (16KB)
  // merge overlay: MO floats on half-1 region (32KB), ML floats on half-0 Vt.

  const int xp = blockIdx.x;                // 0..7
  const int h = blockIdx.y, b = blockIdx.z;
  const int tid = threadIdx.x;
  const int w = tid >> 6, lane = tid & 63;
  const int half = w >> 2, wl = w & 3;
  const int l15 = lane & 15, quad = lane >> 4;
  const size_t base = (size_t)b * T_SEQ * D_MODEL;
  const int hd = h * DKH;

  u16* KtH = (u16*)(smem + half * 32768);
  u16* VtH = (u16*)(smem + half * 32768 + 16384);
  float* ML = (float*)(smem + 16384);
  float* MO = (float*)(smem + 32768);

  // K DMA mapping: 2 gload16/wave/tile, xor-swizzled source dim-blocks
  const int krow = lane >> 3;
  const int kcol = ((lane & 7) ^ krow) * 8;
  const u16* gK = Xk + base + (size_t)(wl * 16 + krow) * D_MODEL + hd + kcol;
  // V staging: thread owns key=lane, dims wl*16..+16; kappa-permuted col + xor blk
  const int vkey = lane;
  const int skey = (vkey & 0x20) | ((vkey & 0xC) << 1) | ((vkey & 0x10) >> 2) | (vkey & 3);
  const int scb = skey >> 3, sci = skey & 7;
  const u16* gV = Xv + base + (size_t)vkey * D_MODEL + hd + wl * 16;

  bf16x8 bones;
#pragma unroll
  for (int i = 0; i < 8; ++i) bones[i] = (short)0x3F80;  // bf16 1.0

  f32x4 zero4 = {0.f, 0.f, 0.f, 0.f};
  int tcnt = 0;

  // preload first tile (k0 = half*64): K DMA -> buf0, V -> regs
  {
    const u16* gk0 = gK + (size_t)(half * 64) * D_MODEL;
    gload16(gk0, KtH + (wl * 16) * 64);
    gload16(gk0 + (size_t)8 * D_MODEL, KtH + (wl * 16 + 8) * 64);
  }
  const u16* gv0 = gV + (size_t)(half * 64) * D_MODEL;
  uint4 va0 = *(const uint4*)gv0;
  uint4 va1 = *(const uint4*)(gv0 + 8);

  for (int ph = 0; ph < 2; ++ph) {
    const int qt = ph ? xp : 15 - xp;       // heavy tile first
    const int q0 = qt << 7;
    const int rowb0 = q0 + wl * 32;

    bf16x8 bq[2][2];
#pragma unroll
    for (int mi = 0; mi < 2; ++mi)
#pragma unroll
      for (int ks = 0; ks < 2; ++ks)
        bq[mi][ks] = *(const bf16x8*)(Xq + base + (size_t)(rowb0 + mi * 16 + l15) * D_MODEL
                                      + hd + ks * 32 + quad * 8);

    f32x4 o[4][2], ol[2];
#pragma unroll
    for (int di = 0; di < 4; ++di)
#pragma unroll
      for (int mi = 0; mi < 2; ++mi) o[di][mi] = zero4;
#pragma unroll
    for (int mi = 0; mi < 2; ++mi) ol[mi] = zero4;

    const int cnt = qt + 1;                 // local tiles this phase (per half)

    // half-1's cross-phase K prefetch was skipped (merge clobbers its region):
    // re-issue here; drained by iteration-0's barrier.
    if (ph == 1 && half == 1) {
      const int fb = tcnt & 1;
      const u16* gk1 = gK + (size_t)64 * D_MODEL;
      gload16(gk1, KtH + fb * 4096 + (wl * 16) * 64);
      gload16(gk1 + (size_t)8 * D_MODEL, KtH + fb * 4096 + (wl * 16 + 8) * 64);
    }

    for (int i = 0; i < cnt; ++i, ++tcnt) {
      const int k0 = (half + 2 * i) * 64;
      const int buf = tcnt & 1;
      u16* ktb = KtH + buf * 4096;
      u16* vtb = VtH + buf * 4096;

      // stage Vt[buf] from held regs
      {
        union { uint4 u; u16 hh[8]; } u0, u1;
        u0.u = va0; u1.u = va1;
#pragma unroll
        for (int ii = 0; ii < 8; ++ii) {
          vtb[(wl * 16 + ii) * 64 + ((scb ^ ii) << 3) + sci] = u0.hh[ii];
          vtb[(wl * 16 + 8 + ii) * 64 + ((scb ^ ii) << 3) + sci] = u1.hh[ii];
        }
      }
      __syncthreads();   // K DMA drained + Vt visible (single barrier per tile)

      // prefetch next local tile (k0+128) or phase-1's first tile
      const bool inph = (i + 1 < cnt);
      if (inph || ph == 0) {
        const int k0n = inph ? k0 + 128 : half * 64;
        if (inph || half == 0) {            // half-1 cross-phase K handled above
          const u16* gk2 = gK + (size_t)k0n * D_MODEL;
          u16* ktn = KtH + (1 - buf) * 4096;
          gload16(gk2, ktn + (wl * 16) * 64);
          gload16(gk2 + (size_t)8 * D_MODEL, ktn + (wl * 16 + 8) * 64);
        }
        const u16* gv2 = gV + (size_t)k0n * D_MODEL;
        va0 = *(const uint4*)gv2;
        va1 = *(const uint4*)(gv2 + 8);
      }

      // S^T = K Q^T, K A-frags from swizzled LDS
      f32x4 st[4][2];
#pragma unroll
      for (int ni = 0; ni < 4; ++ni) {
        const u16* kr = ktb + (ni * 16 + l15) * 64;
        bf16x8 a0 = *(const bf16x8*)(kr + ((quad ^ (l15 & 7)) << 3));
        bf16x8 a1 = *(const bf16x8*)(kr + (((4 + quad) ^ (l15 & 7)) << 3));
#pragma unroll
        for (int mi = 0; mi < 2; ++mi) {
          f32x4 t = zero4;
          t = __builtin_amdgcn_mfma_f32_16x16x32_bf16(a0, bq[mi][0], t, 0, 0, 0);
          t = __builtin_amdgcn_mfma_f32_16x16x32_bf16(a1, bq[mi][1], t, 0, 0, 0);
          st[ni][mi] = t;
        }
      }

      // causal mask + bare-exp2 softmax + in-lane pack (kappa order)
      bf16x8 bp[2][2];
#pragma unroll
      for (int mi = 0; mi < 2; ++mi) {
        const int qa = rowb0 + mi * 16 + l15;
        if (k0 + 63 > rowb0 + mi * 16) {    // wave-uniform: diagonal-ish tiles
#pragma unroll
          for (int ni = 0; ni < 4; ++ni)
#pragma unroll
            for (int r = 0; r < 4; ++r)
              if (k0 + ni * 16 + quad * 4 + r > qa) st[ni][mi][r] = -1e30f;
        }
        float p[4][4];
#pragma unroll
        for (int ni = 0; ni < 4; ++ni)
#pragma unroll
          for (int r = 0; r < 4; ++r)
            p[ni][r] = fexp2(st[ni][mi][r]);
#pragma unroll
        for (int js = 0; js < 2; ++js) {
          union { bf16x8 v; unsigned d[4]; } ub;
          ub.d[0] = pack2(p[2 * js][0], p[2 * js][1]);
          ub.d[1] = pack2(p[2 * js][2], p[2 * js][3]);
          ub.d[2] = pack2(p[2 * js + 1][0], p[2 * js + 1][1]);
          ub.d[3] = pack2(p[2 * js + 1][2], p[2 * js + 1][3]);
          bp[mi][js] = ub.v;
        }
      }

      // O^T += V^T P^T ; ol += 1 P^T
#pragma unroll
      for (int js = 0; js < 2; ++js) {
        bf16x8 av[4];
#pragma unroll
        for (int di = 0; di < 4; ++di)
          av[di] = *(const bf16x8*)(vtb + (di * 16 + l15) * 64
                                    + (((js * 4 + quad) ^ (l15 & 7)) << 3));
#pragma unroll
        for (int di = 0; di < 4; ++di)
#pragma unroll
          for (int mi = 0; mi < 2; ++mi)
            o[di][mi] = __builtin_amdgcn_mfma_f32_16x16x32_bf16(av[di], bp[mi][js], o[di][mi], 0, 0, 0);
#pragma unroll
        for (int mi = 0; mi < 2; ++mi)
          ol[mi] = __builtin_amdgcn_mfma_f32_16x16x32_bf16(bones, bp[mi][js], ol[mi], 0, 0, 0);
      }
    }

    // ---- merge halves (partial sums add directly; no-max softmax) ----
    __syncthreads();                         // B1: all PV reads done
    if (half == 1) {
#pragma unroll
      for (int mi = 0; mi < 2; ++mi) {
        const int ql = wl * 32 + mi * 16 + l15;
        if (quad == 0) ML[ql] = ol[mi][0];
#pragma unroll
        for (int di = 0; di < 4; ++di)
#pragma unroll
          for (int r = 0; r < 4; ++r) {
            const int d = di * 16 + quad * 4 + r;
            MO[ql * 64 + (d ^ ((ql & 7) << 3))] = o[di][mi][r];
          }
      }
    }
    __syncthreads();                         // B2: merge data visible
    if (half == 0) {
#pragma unroll
      for (int mi = 0; mi < 2; ++mi) {
        const int ql = wl * 32 + mi * 16 + l15;
        const float inv = 1.0f / (ol[mi][0] + ML[ql]);
        const size_t qa = q0 + ql;
#pragma unroll
        for (int di = 0; di < 4; ++di) {
          float t[4];
#pragma unroll
          for (int r = 0; r < 4; ++r) {
            const int d = di * 16 + quad * 4 + r;
            t[r] = (o[di][mi][r] + MO[ql * 64 + (d ^ ((ql & 7) << 3))]) * inv;
          }
          uint2 s2;
          s2.x = pack2(t[0], t[1]);
          s2.y = pack2(t[2], t[3]);
          *(uint2*)(O + base + qa * D_MODEL + hd + di * 16 + quad * 4) = s2;
        }
      }
    }
    __syncthreads();                         // B3: merge reads done before reuse
  }
}

// ---------------- launch ----------------
extern "C" void kernel_launch(void* const* d_in, const int* in_sizes, int n_in,
                              void* d_out, int out_size, void* d_ws, size_t ws_size,
                              hipStream_t stream) {
  const float* q   = (const float*)d_in[0];
  const float* k   = (const float*)d_in[1];
  const float* v   = (const float*)d_in[2];
  const float* w_q = (const float*)d_in[4];  const float* b_q = (const float*)d_in[5];
  const float* w_k = (const float*)d_in[6];  const float* b_k = (const float*)d_in[7];
  const float* w_v = (const float*)d_in[8];  const float* b_v = (const float*)d_in[9];
  const float* w_o = (const float*)d_in[10]; const float* b_o = (const float*)d_in[11];

  u16* ws = (u16*)d_ws;
  const size_t NTD = (size_t)NB * T_SEQ * D_MODEL;   // 8388608
  const size_t WSZ = (size_t)D_MODEL * D_MODEL;      // 1048576
  u16* wqb = ws;
  u16* wkb = wqb + WSZ;
  u16* wvb = wkb + WSZ;
  u16* wob = wvb + WSZ;
  u16* Xq  = wob + WSZ;
  u16* Xk  = Xq + NTD;
  u16* Xv  = Xk + NTD;
  u16* Ob  = Xv + NTD;
  // total ws: 4*2MB + 4*16.78MB = 75.5 MB

  cast_w4<<<dim3(WSZ / 1024, 4), 256, 0, stream>>>(w_q, w_k, w_v, w_o, wqb, wkb, wvb, wob);

  gemm_qkv<<<dim3(64, 4, 3), 256, 0, stream>>>(q, k, v, wqb, wkb, wvb,
                                               b_q, b_k, b_v, Xq, Xk, Xv);

  attn_fwd<<<dim3(8, NH, NB), 512, 0, stream>>>(Xq, Xk, Xv, Ob);

  gemm_nt_f32out<<<dim3(64, 8), 256, 0, stream>>>(Ob, wob, b_o, (float*)d_out,
                                                  8192, 1024, 1024);
}

// Round 8
// 345.324 us; speedup vs baseline: 1.2692x; 1.0399x over previous
//
#include <hip/hip_runtime.h>

typedef unsigned short u16;
typedef __attribute__((ext_vector_type(8))) short bf16x8;
typedef __attribute__((ext_vector_type(4))) float f32x4;

#define D_MODEL 1024
#define T_SEQ   2048
#define NB      4
#define NH      16
#define DKH     64

__device__ __forceinline__ u16 f2bf(float x) {
  union { float f; unsigned u; } v; v.f = x;
  unsigned r = v.u + 0x7fffu + ((v.u >> 16) & 1u);
  return (u16)(r >> 16);
}
__device__ __forceinline__ unsigned pack2(float a, float b) {
  return (unsigned)f2bf(a) | ((unsigned)f2bf(b) << 16);
}
__device__ __forceinline__ float fexp2(float x) {
#if __has_builtin(__builtin_amdgcn_exp2f)
  return __builtin_amdgcn_exp2f(x);
#else
  return __expf(x * 0.6931471805599453f);
#endif
}

// async global->LDS, 16B per lane. LDS dest = wave-uniform base + lane*16.
__device__ __forceinline__ void gload16(const void* g, void* l) {
  __builtin_amdgcn_global_load_lds(
      (const __attribute__((address_space(1))) unsigned*)g,
      (__attribute__((address_space(3))) unsigned*)l, 16, 0, 0);
}

// ---------------- cast 4 weight matrices fp32 -> bf16 ----------------
__global__ void cast_w4(const float* __restrict__ s0, const float* __restrict__ s1,
                        const float* __restrict__ s2, const float* __restrict__ s3,
                        u16* __restrict__ o0, u16* __restrict__ o1,
                        u16* __restrict__ o2, u16* __restrict__ o3) {
  const int which = blockIdx.y;
  const float* s = which == 0 ? s0 : which == 1 ? s1 : which == 2 ? s2 : s3;
  u16* o = which == 0 ? o0 : which == 1 ? o1 : which == 2 ? o2 : o3;
  int i = ((int)blockIdx.x * 256 + (int)threadIdx.x) * 4;
  float4 v = *(const float4*)(s + i);
  uint2 u; u.x = pack2(v.x, v.y); u.y = pack2(v.z, v.w);
  *(uint2*)(o + i) = u;
}

// ---------------- fused QKV projection v8: single-barrier pipelined K-loop ----------------
// grid (64, 8, 3); z selects (q,k,v). C = A@W^T + bias, bf16 out.
// 128x128 tile, 4 waves (2x2 of 64x64). As: fp32 loaded to regs one K-step ahead,
// VALU-cast, conflict-free xor-swizzled ds_write, dbuf. Bs: async DMA issued one
// K-step ahead (post-barrier), dbuf. ONE barrier per K-step -> DMA/loads have a
// full MFMA section in flight when the barrier's vmcnt(0) drain hits.
// Q output pre-scaled by log2(e)/8 (bare-exp2 softmax downstream).
__global__ __launch_bounds__(256) void gemm_qkv(
    const float* __restrict__ qin, const float* __restrict__ kin, const float* __restrict__ vin,
    const u16* __restrict__ wq, const u16* __restrict__ wk, const u16* __restrict__ wv,
    const float* __restrict__ bqp, const float* __restrict__ bkp, const float* __restrict__ bvp,
    u16* __restrict__ Xq, u16* __restrict__ Xk, u16* __restrict__ Xv) {
  const int z = blockIdx.z;
  const float* A = z == 0 ? qin : z == 1 ? kin : vin;
  const u16* W = z == 0 ? wq : z == 1 ? wk : wv;
  const float* bias = z == 0 ? bqp : z == 1 ? bkp : bvp;
  u16* C = z == 0 ? Xq : z == 1 ? Xk : Xv;
  const float osc = z == 0 ? 0.18033688011112042f : 1.0f;  // log2(e)/8
  const int K = 1024, N = 1024;

  __shared__ __align__(16) u16 As[2][8192];   // 2 x 16 KB
  __shared__ __align__(16) u16 Bs[2][8192];   // 2 x 16 KB
  const int tid = threadIdx.x;
  const int w = tid >> 6, lane = tid & 63;
  const int wm = w & 1, wn = w >> 1;
  const int l15 = lane & 15, quad = lane >> 4;
  const int l8 = lane >> 3, l7 = lane & 7;
  const int m0 = blockIdx.x * 128, n0 = blockIdx.y * 128;
  const int sb = l7 ^ l8;   // source col-block for swizzled staging

  // A source: inst j covers rows w*32+j*8+l8, src block sb (fp32)
  const float* gA = A + (size_t)(m0 + w * 32 + l8) * K + sb * 8;
  // B source: same mapping in bf16
  const u16* gB = W + (size_t)(n0 + w * 32 + l8) * K + sb * 8;

  f32x4 zero4 = {0.f, 0.f, 0.f, 0.f};
  f32x4 acc[4][4];
#pragma unroll
  for (int i = 0; i < 4; ++i)
#pragma unroll
    for (int j = 0; j < 4; ++j) acc[i][j] = zero4;

  // preload K-step 0: A fp32 -> regs, B DMA -> Bs[0]
  float4 a0[4], a1[4];
#pragma unroll
  for (int j = 0; j < 4; ++j) {
    const float* p = gA + (size_t)(j * 8) * K;
    a0[j] = *(const float4*)p;
    a1[j] = *(const float4*)(p + 4);
  }
#pragma unroll
  for (int j = 0; j < 4; ++j)
    gload16(gB + (size_t)(j * 8) * K, Bs[0] + (w * 32 + j * 8) * 64);

  for (int kbi = 0; kbi < 16; ++kbi) {
    const int buf = kbi & 1;

    // pack + conflict-free swizzled write of As[buf] (dest block = l7)
#pragma unroll
    for (int j = 0; j < 4; ++j) {
      uint4 wv;
      wv.x = pack2(a0[j].x, a0[j].y); wv.y = pack2(a0[j].z, a0[j].w);
      wv.z = pack2(a1[j].x, a1[j].y); wv.w = pack2(a1[j].z, a1[j].w);
      *(uint4*)(As[buf] + (w * 32 + j * 8 + l8) * 64 + l7 * 8) = wv;
    }
    __syncthreads();   // drains: B DMA for kbi (in flight all prev MFMA) + As writes

    if (kbi < 15) {
      const int kb2 = (kbi + 1) * 64;
#pragma unroll
      for (int j = 0; j < 4; ++j)
        gload16(gB + kb2 + (size_t)(j * 8) * K, Bs[1 - buf] + (w * 32 + j * 8) * 64);
#pragma unroll
      for (int j = 0; j < 4; ++j) {
        const float* p = gA + kb2 + (size_t)(j * 8) * K;
        a0[j] = *(const float4*)p;
        a1[j] = *(const float4*)(p + 4);
      }
    }

#pragma unroll
    for (int ks = 0; ks < 2; ++ks) {
      const int sw = ((ks * 4 + quad) ^ (l15 & 7)) * 8;
      bf16x8 af[4], bfr[4];
#pragma unroll
      for (int i = 0; i < 4; ++i)
        af[i] = *(const bf16x8*)(As[buf] + (wm * 64 + i * 16 + l15) * 64 + sw);
#pragma unroll
      for (int i = 0; i < 4; ++i)
        bfr[i] = *(const bf16x8*)(Bs[buf] + (wn * 64 + i * 16 + l15) * 64 + sw);
#pragma unroll
      for (int mi = 0; mi < 4; ++mi)
#pragma unroll
        for (int ni = 0; ni < 4; ++ni)
          acc[mi][ni] = __builtin_amdgcn_mfma_f32_16x16x32_bf16(af[mi], bfr[ni], acc[mi][ni], 0, 0, 0);
    }
  }

#pragma unroll
  for (int ni = 0; ni < 4; ++ni) {
    int col = n0 + wn * 64 + ni * 16 + l15;
    float bv = bias[col];
#pragma unroll
    for (int mi = 0; mi < 4; ++mi) {
      int row = m0 + wm * 64 + mi * 16 + quad * 4;
#pragma unroll
      for (int r = 0; r < 4; ++r)
        C[(size_t)(row + r) * N + col] = f2bf((acc[mi][ni][r] + bv) * osc);
    }
  }
}

// ---------------- O-projection v8: both operands async, single-barrier loop ----------------
__global__ __launch_bounds__(256) void gemm_nt_f32out(const u16* __restrict__ Ab,
                                                      const u16* __restrict__ W,
                                                      const float* __restrict__ bias,
                                                      float* __restrict__ Cp,
                                                      int M, int N, int K) {
  __shared__ __align__(16) u16 As[2][8192];
  __shared__ __align__(16) u16 Bs[2][8192];
  const int tid = threadIdx.x;
  const int w = tid >> 6, lane = tid & 63;
  const int wm = w & 1, wn = w >> 1;
  const int l15 = lane & 15, quad = lane >> 4;
  const int l8 = lane >> 3, l7 = lane & 7;
  const int m0 = blockIdx.x * 128, n0 = blockIdx.y * 128;
  const int sb = l7 ^ l8;

  const u16* gA = Ab + (size_t)(m0 + w * 32 + l8) * K + sb * 8;
  const u16* gB = W  + (size_t)(n0 + w * 32 + l8) * K + sb * 8;

  f32x4 zero4 = {0.f, 0.f, 0.f, 0.f};
  f32x4 acc[4][4];
#pragma unroll
  for (int i = 0; i < 4; ++i)
#pragma unroll
    for (int j = 0; j < 4; ++j) acc[i][j] = zero4;

  // preload K-step 0
#pragma unroll
  for (int j = 0; j < 4; ++j) {
    gload16(gA + (size_t)(j * 8) * K, As[0] + (w * 32 + j * 8) * 64);
    gload16(gB + (size_t)(j * 8) * K, Bs[0] + (w * 32 + j * 8) * 64);
  }

  for (int kbi = 0; kbi < 16; ++kbi) {
    const int buf = kbi & 1;
    __syncthreads();   // drains DMA for kbi (in flight during prev MFMA section)

    if (kbi < 15) {
      const int kb2 = (kbi + 1) * 64;
#pragma unroll
      for (int j = 0; j < 4; ++j) {
        gload16(gA + kb2 + (size_t)(j * 8) * K, As[1 - buf] + (w * 32 + j * 8) * 64);
        gload16(gB + kb2 + (size_t)(j * 8) * K, Bs[1 - buf] + (w * 32 + j * 8) * 64);
      }
    }

#pragma unroll
    for (int ks = 0; ks < 2; ++ks) {
      const int sw = ((ks * 4 + quad) ^ (l15 & 7)) * 8;
      bf16x8 af[4], bfr[4];
#pragma unroll
      for (int i = 0; i < 4; ++i)
        af[i] = *(const bf16x8*)(As[buf] + (wm * 64 + i * 16 + l15) * 64 + sw);
#pragma unroll
      for (int i = 0; i < 4; ++i)
        bfr[i] = *(const bf16x8*)(Bs[buf] + (wn * 64 + i * 16 + l15) * 64 + sw);
#pragma unroll
      for (int mi = 0; mi < 4; ++mi)
#pragma unroll
        for (int ni = 0; ni < 4; ++ni)
          acc[mi][ni] = __builtin_amdgcn_mfma_f32_16x16x32_bf16(af[mi], bfr[ni], acc[mi][ni], 0, 0, 0);
    }
  }

#pragma unroll
  for (int ni = 0; ni < 4; ++ni) {
    int col = n0 + wn * 64 + ni * 16 + l15;
    float bv = bias[col];
#pragma unroll
    for (int mi = 0; mi < 4; ++mi) {
      int row = m0 + wm * 64 + mi * 16 + quad * 4;
#pragma unroll
      for (int r = 0; r < 4; ++r)
        Cp[(size_t)(row + r) * N + col] = acc[mi][ni][r] + bv;
    }
  }
}

// ---------------- causal flash attention (unchanged from r7) ----------------
__global__ __launch_bounds__(512, 2) void attn_fwd(const u16* __restrict__ Xq,
                                                   const u16* __restrict__ Xk,
                                                   const u16* __restrict__ Xv,
                                                   u16* __restrict__ O) {
  __shared__ __align__(16) char smem[65536];

  const int xp = blockIdx.x;                // 0..7
  const int h = blockIdx.y, b = blockIdx.z;
  const int tid = threadIdx.x;
  const int w = tid >> 6, lane = tid & 63;
  const int half = w >> 2, wl = w & 3;
  const int l15 = lane & 15, quad = lane >> 4;
  const size_t base = (size_t)b * T_SEQ * D_MODEL;
  const int hd = h * DKH;

  u16* KtH = (u16*)(smem + half * 32768);
  u16* VtH = (u16*)(smem + half * 32768 + 16384);
  float* ML = (float*)(smem + 16384);
  float* MO = (float*)(smem + 32768);

  const int krow = lane >> 3;
  const int kcol = ((lane & 7) ^ krow) * 8;
  const u16* gK = Xk + base + (size_t)(wl * 16 + krow) * D_MODEL + hd + kcol;
  const int vkey = lane;
  const int skey = (vkey & 0x20) | ((vkey & 0xC) << 1) | ((vkey & 0x10) >> 2) | (vkey & 3);
  const int scb = skey >> 3, sci = skey & 7;
  const u16* gV = Xv + base + (size_t)vkey * D_MODEL + hd + wl * 16;

  bf16x8 bones;
#pragma unroll
  for (int i = 0; i < 8; ++i) bones[i] = (short)0x3F80;  // bf16 1.0

  f32x4 zero4 = {0.f, 0.f, 0.f, 0.f};
  int tcnt = 0;

  {
    const u16* gk0 = gK + (size_t)(half * 64) * D_MODEL;
    gload16(gk0, KtH + (wl * 16) * 64);
    gload16(gk0 + (size_t)8 * D_MODEL, KtH + (wl * 16 + 8) * 64);
  }
  const u16* gv0 = gV + (size_t)(half * 64) * D_MODEL;
  uint4 va0 = *(const uint4*)gv0;
  uint4 va1 = *(const uint4*)(gv0 + 8);

  for (int ph = 0; ph < 2; ++ph) {
    const int qt = ph ? xp : 15 - xp;
    const int q0 = qt << 7;
    const int rowb0 = q0 + wl * 32;

    bf16x8 bq[2][2];
#pragma unroll
    for (int mi = 0; mi < 2; ++mi)
#pragma unroll
      for (int ks = 0; ks < 2; ++ks)
        bq[mi][ks] = *(const bf16x8*)(Xq + base + (size_t)(rowb0 + mi * 16 + l15) * D_MODEL
                                      + hd + ks * 32 + quad * 8);

    f32x4 o[4][2], ol[2];
#pragma unroll
    for (int di = 0; di < 4; ++di)
#pragma unroll
      for (int mi = 0; mi < 2; ++mi) o[di][mi] = zero4;
#pragma unroll
    for (int mi = 0; mi < 2; ++mi) ol[mi] = zero4;

    const int cnt = qt + 1;

    if (ph == 1 && half == 1) {
      const int fb = tcnt & 1;
      const u16* gk1 = gK + (size_t)64 * D_MODEL;
      gload16(gk1, KtH + fb * 4096 + (wl * 16) * 64);
      gload16(gk1 + (size_t)8 * D_MODEL, KtH + fb * 4096 + (wl * 16 + 8) * 64);
    }

    for (int i = 0; i < cnt; ++i, ++tcnt) {
      const int k0 = (half + 2 * i) * 64;
      const int buf = tcnt & 1;
      u16* ktb = KtH + buf * 4096;
      u16* vtb = VtH + buf * 4096;

      {
        union { uint4 u; u16 hh[8]; } u0, u1;
        u0.u = va0; u1.u = va1;
#pragma unroll
        for (int ii = 0; ii < 8; ++ii) {
          vtb[(wl * 16 + ii) * 64 + ((scb ^ ii) << 3) + sci] = u0.hh[ii];
          vtb[(wl * 16 + 8 + ii) * 64 + ((scb ^ ii) << 3) + sci] = u1.hh[ii];
        }
      }
      __syncthreads();

      const bool inph = (i + 1 < cnt);
      if (inph || ph == 0) {
        const int k0n = inph ? k0 + 128 : half * 64;
        if (inph || half == 0) {
          const u16* gk2 = gK + (size_t)k0n * D_MODEL;
          u16* ktn = KtH + (1 - buf) * 4096;
          gload16(gk2, ktn + (wl * 16) * 64);
          gload16(gk2 + (size_t)8 * D_MODEL, ktn + (wl * 16 + 8) * 64);
        }
        const u16* gv2 = gV + (size_t)k0n * D_MODEL;
        va0 = *(const uint4*)gv2;
        va1 = *(const uint4*)(gv2 + 8);
      }

      f32x4 st[4][2];
#pragma unroll
      for (int ni = 0; ni < 4; ++ni) {
        const u16* kr = ktb + (ni * 16 + l15) * 64;
        bf16x8 a0 = *(const bf16x8*)(kr + ((quad ^ (l15 & 7)) << 3));
        bf16x8 a1 = *(const bf16x8*)(kr + (((4 + quad) ^ (l15 & 7)) << 3));
#pragma unroll
        for (int mi = 0; mi < 2; ++mi) {
          f32x4 t = zero4;
          t = __builtin_amdgcn_mfma_f32_16x16x32_bf16(a0, bq[mi][0], t, 0, 0, 0);
          t = __builtin_amdgcn_mfma_f32_16x16x32_bf16(a1, bq[mi][1], t, 0, 0, 0);
          st[ni][mi] = t;
        }
      }

      bf16x8 bp[2][2];
#pragma unroll
      for (int mi = 0; mi < 2; ++mi) {
        const int qa = rowb0 + mi * 16 + l15;
        if (k0 + 63 > rowb0 + mi * 16) {
#pragma unroll
          for (int ni = 0; ni < 4; ++ni)
#pragma unroll
            for (int r = 0; r < 4; ++r)
              if (k0 + ni * 16 + quad * 4 + r > qa) st[ni][mi][r] = -1e30f;
        }
        float p[4][4];
#pragma unroll
        for (int ni = 0; ni < 4; ++ni)
#pragma unroll
          for (int r = 0; r < 4; ++r)
            p[ni][r] = fexp2(st[ni][mi][r]);
#pragma unroll
        for (int js = 0; js < 2; ++js) {
          union { bf16x8 v; unsigned d[4]; } ub;
          ub.d[0] = pack2(p[2 * js][0], p[2 * js][1]);
          ub.d[1] = pack2(p[2 * js][2], p[2 * js][3]);
          ub.d[2] = pack2(p[2 * js + 1][0], p[2 * js + 1][1]);
          ub.d[3] = pack2(p[2 * js + 1][2], p[2 * js + 1][3]);
          bp[mi][js] = ub.v;
        }
      }

#pragma unroll
      for (int js = 0; js < 2; ++js) {
        bf16x8 av[4];
#pragma unroll
        for (int di = 0; di < 4; ++di)
          av[di] = *(const bf16x8*)(vtb + (di * 16 + l15) * 64
                                    + (((js * 4 + quad) ^ (l15 & 7)) << 3));
#pragma unroll
        for (int di = 0; di < 4; ++di)
#pragma unroll
          for (int mi = 0; mi < 2; ++mi)
            o[di][mi] = __builtin_amdgcn_mfma_f32_16x16x32_bf16(av[di], bp[mi][js], o[di][mi], 0, 0, 0);
#pragma unroll
        for (int mi = 0; mi < 2; ++mi)
          ol[mi] = __builtin_amdgcn_mfma_f32_16x16x32_bf16(bones, bp[mi][js], ol[mi], 0, 0, 0);
      }
    }

    __syncthreads();
    if (half == 1) {
#pragma unroll
      for (int mi = 0; mi < 2; ++mi) {
        const int ql = wl * 32 + mi * 16 + l15;
        if (quad == 0) ML[ql] = ol[mi][0];
#pragma unroll
        for (int di = 0; di < 4; ++di)
#pragma unroll
          for (int r = 0; r < 4; ++r) {
            const int d = di * 16 + quad * 4 + r;
            MO[ql * 64 + (d ^ ((ql & 7) << 3))] = o[di][mi][r];
          }
      }
    }
    __syncthreads();
    if (half == 0) {
#pragma unroll
      for (int mi = 0; mi < 2; ++mi) {
        const int ql = wl * 32 + mi * 16 + l15;
        const float inv = 1.0f / (ol[mi][0] + ML[ql]);
        const size_t qa = q0 + ql;
#pragma unroll
        for (int di = 0; di < 4; ++di) {
          float t[4];
#pragma unroll
          for (int r = 0; r < 4; ++r) {
            const int d = di * 16 + quad * 4 + r;
            t[r] = (o[di][mi][r] + MO[ql * 64 + (d ^ ((ql & 7) << 3))]) * inv;
          }
          uint2 s2;
          s2.x = pack2(t[0], t[1]);
          s2.y = pack2(t[2], t[3]);
          *(uint2*)(O + base + qa * D_MODEL + hd + di * 16 + quad * 4) = s2;
        }
      }
    }
    __syncthreads();
  }
}

// ---------------- launch ----------------
extern "C" void kernel_launch(void* const* d_in, const int* in_sizes, int n_in,
                              void* d_out, int out_size, void* d_ws, size_t ws_size,
                              hipStream_t stream) {
  const float* q   = (const float*)d_in[0];
  const float* k   = (const float*)d_in[1];
  const float* v   = (const float*)d_in[2];
  const float* w_q = (const float*)d_in[4];  const float* b_q = (const float*)d_in[5];
  const float* w_k = (const float*)d_in[6];  const float* b_k = (const float*)d_in[7];
  const float* w_v = (const float*)d_in[8];  const float* b_v = (const float*)d_in[9];
  const float* w_o = (const float*)d_in[10]; const float* b_o = (const float*)d_in[11];

  u16* ws = (u16*)d_ws;
  const size_t NTD = (size_t)NB * T_SEQ * D_MODEL;   // 8388608
  const size_t WSZ = (size_t)D_MODEL * D_MODEL;      // 1048576
  u16* wqb = ws;
  u16* wkb = wqb + WSZ;
  u16* wvb = wkb + WSZ;
  u16* wob = wvb + WSZ;
  u16* Xq  = wob + WSZ;
  u16* Xk  = Xq + NTD;
  u16* Xv  = Xk + NTD;
  u16* Ob  = Xv + NTD;
  // total ws: 4*2MB + 4*16.78MB = 75.5 MB

  cast_w4<<<dim3(WSZ / 1024, 4), 256, 0, stream>>>(w_q, w_k, w_v, w_o, wqb, wkb, wvb, wob);

  gemm_qkv<<<dim3(64, 8, 3), 256, 0, stream>>>(q, k, v, wqb, wkb, wvb,
                                               b_q, b_k, b_v, Xq, Xk, Xv);

  attn_fwd<<<dim3(8, NH, NB), 512, 0, stream>>>(Xq, Xk, Xv, Ob);

  gemm_nt_f32out<<<dim3(64, 8), 256, 0, stream>>>(Ob, wob, b_o, (float*)d_out,
                                                  8192, 1024, 1024);
}